// Round 8
// baseline (396.155 us; speedup 1.0000x reference)
//
#include <hip/hip_runtime.h>
#include <math.h>

#define BSZ 4
#define Lseq 2048
#define DM 64
#define ED 128
#define NST 32
#define DCONVK 16
#define NLAYERS 4
#define DTRANK 4
#define EPSV 1e-5f
#define NC 128                // chunks along L (chunk == conv tile == gemm tile)
#define TT 16                 // tokens per block
#define NSEG 8                // combine: segments per (b,e,n) scan
#define GRIDN (BSZ * NC)      // 512 blocks; co-resident at 2 blocks/CU
#define L2E 1.4426950408889634f

#if defined(__has_builtin)
#if __has_builtin(__builtin_amdgcn_exp2f)
#define EXP2F(x) __builtin_amdgcn_exp2f(x)
#else
#define EXP2F(x) exp2f(x)
#endif
#else
#define EXP2F(x) exp2f(x)
#endif

__device__ __forceinline__ float sigf(float x) { return 1.0f / (1.0f + __expf(-x)); }
__device__ __forceinline__ float hsum4(float4 a) { return (a.x + a.y) + (a.z + a.w); }

// Coherence discipline (R4-R7 lessons): cross-block data sc1 both sides
// (lane-contiguous!), same-block data plain both sides. No cache-maintenance
// ops anywhere (wb/inv storms cost 76us/barrier in R3).
__device__ __forceinline__ float ldsc(const float* p) {
    return __hip_atomic_load((float*)p, __ATOMIC_RELAXED, __HIP_MEMORY_SCOPE_AGENT);
}
__device__ __forceinline__ void stsc(float* p, float v) {
    __hip_atomic_store(p, v, __ATOMIC_RELAXED, __HIP_MEMORY_SCOPE_AGENT);
}
__device__ __forceinline__ unsigned long long ldsc64(const void* p) {
    return __hip_atomic_load((unsigned long long*)p, __ATOMIC_RELAXED,
                             __HIP_MEMORY_SCOPE_AGENT);
}
__device__ __forceinline__ void stsc64(void* p, unsigned long long v) {
    __hip_atomic_store((unsigned long long*)p, v, __ATOMIC_RELAXED,
                       __HIP_MEMORY_SCOPE_AGENT);
}
__device__ __forceinline__ unsigned int ldu(const unsigned int* p) {
    return __hip_atomic_load((unsigned int*)p, __ATOMIC_RELAXED,
                             __HIP_MEMORY_SCOPE_AGENT);
}

// Per-BATCH barrier: 128 arrivals on one padded counter (R7's grid barrier
// gated all 512 blocks on the globally slowest; dependencies are per-batch,
// so batches now slide past each other — co-resident blocks of different
// batches fill each other's stalls). Monotonic counter; target=(li+1)*128.
__device__ __forceinline__ void bbar(unsigned int* cnt, unsigned int target)
{
    __syncthreads();   // drains all waves' stores (vmcnt) before arrival
    if (threadIdx.x == 0) {
        __hip_atomic_fetch_add(cnt, 1u, __ATOMIC_RELAXED, __HIP_MEMORY_SCOPE_AGENT);
        while (ldu(cnt) < target)
            __builtin_amdgcn_s_sleep(1);
    }
    __builtin_amdgcn_sched_barrier(0);
    __syncthreads();
}

// inproj: 64 -> 256 for 16 tokens. xin/zbuf PLAIN (same-block, L2-hot);
// cross-block consumers get sc1 duplicates: rows 1..15 -> halo buffer
// (neighbor's conv halo), last token's z -> zbH (head).
__device__ __forceinline__ void inproj16(
    const float* in_w_l, const float* in_b_l, const float (*hn)[DM],
    float* xin, float* zbuf, float* haloW, float* zbH_b, bool lastChunk,
    size_t t0, int tid)
{
    float4 w4[16];
    const float4* wr = (const float4*)(in_w_l + tid * DM);
    #pragma unroll
    for (int i = 0; i < 16; ++i) w4[i] = wr[i];
    const float bias = in_b_l[tid];
    #pragma unroll 2
    for (int tok = 0; tok < TT; ++tok) {
        const float4* hv4 = (const float4*)&hn[tok][0];
        float4 a4 = make_float4(0.f, 0.f, 0.f, 0.f);
        #pragma unroll
        for (int i = 0; i < 16; ++i) {
            float4 hv = hv4[i];
            a4.x = fmaf(hv.x, w4[i].x, a4.x);
            a4.y = fmaf(hv.y, w4[i].y, a4.y);
            a4.z = fmaf(hv.z, w4[i].z, a4.z);
            a4.w = fmaf(hv.w, w4[i].w, a4.w);
        }
        const float r = bias + hsum4(a4);
        if (tid < ED) {
            xin[(t0 + tok) * ED + tid] = r;
            if (tok >= 1) stsc(&haloW[(tok - 1) * ED + tid], r);
        } else {
            zbuf[(t0 + tok) * ED + (tid - ED)] = r;
            if (lastChunk && tok == TT - 1) stsc(&zbH_b[tid - ED], r);
        }
    }
}

struct KParams {
    const float *x, *in_w, *in_b, *conv_w, *conv_b, *xproj_w, *dtproj_w,
                *dtproj_b, *A_log, *Dp, *outproj_w, *outproj_b, *norm_w,
                *fc_w, *fc_b;
    float *out, *h0, *h1, *xin, *zbuf, *xc, *dlt, *Bv, *Cv, *dsum, *hloc,
          *H, *zbH;
    unsigned int *cntA, *cntB, *hflag;
};

__global__ __launch_bounds__(256, 2) void k_mamba(KParams P)
{
    const int bid = blockIdx.x;            // 512 = BSZ*NC
    const int tid = threadIdx.x;           // 256
    const int bb = bid >> 7, cc = bid & 127;
    __shared__ __align__(16) float smem[12288];   // 48 KB, phase-aliased

    const bool lastChunk = (cc == NC - 1);
    float* haloW = P.H + (size_t)bid * ((DCONVK - 1) * ED);
    float* zbH_b = P.zbH + (size_t)bb * ED;
    unsigned int* cA = P.cntA + bb * 64;
    unsigned int* cB = P.cntB + bb * 64;

    // ================= layer 0: rmsnorm(x) + inproj =================
    {
        float (*hn)[DM] = (float (*)[DM])smem;
        const size_t t0 = (size_t)bid * TT;
        const int lane = tid & 63, wv = tid >> 6;
        const float nw = P.norm_w[lane];
        float hval[4];
        #pragma unroll
        for (int j = 0; j < 4; ++j)
            hval[j] = P.x[(t0 + wv * 4 + j) * DM + lane];
        #pragma unroll
        for (int j = 0; j < 4; ++j) {
            float ss = hval[j] * hval[j];
            #pragma unroll
            for (int off = 32; off; off >>= 1) ss += __shfl_xor(ss, off, 64);
            const float sc = rsqrtf(ss * (1.0f / DM) + EPSV);
            hn[wv * 4 + j][lane] = hval[j] * sc * nw;
        }
        __syncthreads();
        inproj16(P.in_w, P.in_b, (const float (*)[DM])hn, P.xin, P.zbuf,
                 haloW, zbH_b, lastChunk, t0, tid);
    }
    __syncthreads();   // drain halo stores, then publish epoch 1
    if (tid == 0)
        __hip_atomic_store(&P.hflag[bid * 16], 1u, __ATOMIC_RELAXED,
                           __HIP_MEMORY_SCOPE_AGENT);

    #pragma unroll 1
    for (int li = 0; li < NLAYERS; ++li) {
        const int last = (li == NLAYERS - 1);
        const float* Alog = P.A_log + (size_t)li * ED * NST;
        const float* Dpl  = P.Dp + (size_t)li * ED;

        // ============ A: conv + silu + xproj + dtproj + local scan ============
        {
            const int b = bb, c = cc;
            const int l0 = c * TT;
            const size_t t0 = (size_t)b * Lseq + l0;
            const int e = tid & 127, half = tid >> 7;
            const int store_dbc = last ? 0 : 1;
            const bool doXC = store_dbc || (c == NC - 1);

            float* xs = smem;                                   // 3968 floats
            float (*xcs)[ED] = (float (*)[ED])(smem + 4096);    // 2048
            float (*Bs)[NST] = (float (*)[NST])(smem + 6144);   // 512
            float (*dts)[DTRANK] = (float (*)[DTRANK])(smem + 6656); // 64
            float* hsT = smem + 6720;                           // [128][33] = 4224
            float (*dl)[ED] = (float (*)[ED])xs;  // alias: xs dead after conv

            const float* conv_w   = P.conv_w + (size_t)li * ED * DCONVK;
            const float* conv_b   = P.conv_b + (size_t)li * ED;
            const float* xproj_w  = P.xproj_w + (size_t)li * (DTRANK + 2 * NST) * ED;
            const float* dtproj_w = P.dtproj_w + (size_t)li * ED * DTRANK;
            const float* dtproj_b = P.dtproj_b + (size_t)li * ED;

            float Aen16[16];
            {
                const float4* a4 = (const float4*)(Alog + e * NST + half * 16);
                #pragma unroll
                for (int i = 0; i < 4; ++i) {
                    float4 v = a4[i];
                    Aen16[i*4+0] = -__expf(v.x) * L2E; Aen16[i*4+1] = -__expf(v.y) * L2E;
                    Aen16[i*4+2] = -__expf(v.z) * L2E; Aen16[i*4+3] = -__expf(v.w) * L2E;
                }
            }
            float w[DCONVK];
            {
                const float4* cw = (const float4*)(conv_w + e * DCONVK);
                #pragma unroll
                for (int i = 0; i < 4; ++i) {
                    float4 cc4 = cw[i];
                    w[i*4+0] = cc4.x; w[i*4+1] = cc4.y; w[i*4+2] = cc4.z; w[i*4+3] = cc4.w;
                }
            }
            const float cb = conv_b[e];

            {   // own rows 15..30 from xin (plain, same-block L2)
                float4 ov[2];
                #pragma unroll
                for (int i = 0; i < 2; ++i) {
                    const int idx4 = 480 + tid + i * 256;    // rows 15..30
                    const int row = idx4 >> 5;
                    const int lrow = l0 - (DCONVK - 1) + row;  // >= l0 >= 0
                    ov[i] = ((const float4*)(P.xin + ((size_t)b * Lseq + lrow) * ED))[idx4 & 31];
                }
                #pragma unroll
                for (int i = 0; i < 2; ++i)
                    ((float4*)xs)[480 + tid + i * 256] = ov[i];
            }
            // neighbor halo handshake (replaces a full grid barrier):
            // block bid-1's inproj published epoch li+1 for this layer's halo
            if (tid == 0 && c > 0) {
                while (ldu(&P.hflag[(bid - 1) * 16]) < (unsigned)(li + 1))
                    __builtin_amdgcn_s_sleep(2);
            }
            __builtin_amdgcn_sched_barrier(0);
            __syncthreads();
            {   // halo rows 0..14 from H[bid-1] (sc1, cross-block)
                float hv[8];
                #pragma unroll
                for (int i = 0; i < 8; ++i) {
                    const int idx = tid + i * 256;
                    float val = 0.f;
                    if (idx < (DCONVK - 1) * ED && c > 0)
                        val = ldsc(P.H + (size_t)(bid - 1) * ((DCONVK - 1) * ED) + idx);
                    hv[i] = val;
                }
                #pragma unroll
                for (int i = 0; i < 8; ++i) {
                    const int idx = tid + i * 256;
                    if (idx < (DCONVK - 1) * ED) xs[idx] = hv[i];
                }
            }
            __syncthreads();

            {   // conv + silu
                #pragma unroll 2
                for (int j = 0; j < 8; ++j) {
                    const int tok = half * 8 + j;
                    float acc = cb;
                    #pragma unroll
                    for (int k = 0; k < DCONVK; ++k)
                        acc = fmaf(xs[(tok + k) * ED + e], w[k], acc);
                    const float xcv = acc * sigf(acc);
                    xcs[tok][e] = xcv;
                    if (doXC) {
                        if (store_dbc) P.xc[(t0 + tok) * ED + e] = xcv;      // same-block
                        else           stsc(&P.xc[(t0 + tok) * ED + e], xcv); // head x-block
                    }
                }
            }
            __syncthreads();   // xs dead from here on

            {   // xproj
                const int wv = tid >> 6, lane = tid & 63;
                float4 acc[4];
                #pragma unroll
                for (int j = 0; j < 4; ++j) acc[j] = make_float4(0.f, 0.f, 0.f, 0.f);
                #pragma unroll 1
                for (int p = 0; p < 4; ++p) {
                    float4 w4[8];
                    const float4* wr = (const float4*)(xproj_w + lane * ED + p * 32);
                    #pragma unroll
                    for (int i = 0; i < 8; ++i) w4[i] = wr[i];
                    #pragma unroll
                    for (int j = 0; j < 4; ++j) {
                        const float4* yv = (const float4*)&xcs[wv * 4 + j][p * 32];
                        #pragma unroll
                        for (int i = 0; i < 8; ++i) {
                            float4 hv = yv[i];
                            acc[j].x = fmaf(hv.x, w4[i].x, acc[j].x);
                            acc[j].y = fmaf(hv.y, w4[i].y, acc[j].y);
                            acc[j].z = fmaf(hv.z, w4[i].z, acc[j].z);
                            acc[j].w = fmaf(hv.w, w4[i].w, acc[j].w);
                        }
                    }
                }
                #pragma unroll
                for (int j = 0; j < 4; ++j) {
                    const int tok = wv * 4 + j;
                    const float v = hsum4(acc[j]);
                    if (lane < DTRANK) {
                        dts[tok][lane] = v;
                    } else if (lane < DTRANK + NST) {
                        Bs[tok][lane - DTRANK] = v;
                        if (store_dbc) P.Bv[(t0 + tok) * NST + (lane - DTRANK)] = v;
                    } else {
                        if (doXC) {
                            const int ci = lane - DTRANK - NST;
                            if (store_dbc) P.Cv[(t0 + tok) * NST + ci] = v;
                            else           stsc(&P.Cv[(t0 + tok) * NST + ci], v);
                        }
                    }
                }
                {
                    const int ridx = lane & 3;
                    const int ks   = (lane >> 2) & 3;
                    const int tsub = lane >> 4;
                    const int r4   = 64 + ridx;
                    const int tok  = wv * 4 + tsub;
                    const float4* wr = (const float4*)(xproj_w + r4 * ED + ks * 32);
                    const float4* yv = (const float4*)&xcs[tok][ks * 32];
                    float4 a4 = make_float4(0.f, 0.f, 0.f, 0.f);
                    #pragma unroll
                    for (int i = 0; i < 8; ++i) {
                        float4 hv = yv[i]; float4 wv4 = wr[i];
                        a4.x = fmaf(hv.x, wv4.x, a4.x);
                        a4.y = fmaf(hv.y, wv4.y, a4.y);
                        a4.z = fmaf(hv.z, wv4.z, a4.z);
                        a4.w = fmaf(hv.w, wv4.w, a4.w);
                    }
                    float v = hsum4(a4);
                    v += __shfl_xor(v, 4, 64);
                    v += __shfl_xor(v, 8, 64);
                    if (ks == 0 && doXC) {
                        const int ci = r4 - DTRANK - NST;
                        if (store_dbc) P.Cv[(t0 + tok) * NST + ci] = v;
                        else           stsc(&P.Cv[(t0 + tok) * NST + ci], v);
                    }
                }
            }
            __syncthreads();

            {   // dtproj + softplus -> dl (aliased LDS) + delta_out
                const float4 dwv = *(const float4*)(dtproj_w + e * DTRANK);
                const float bias = dtproj_b[e];
                #pragma unroll 2
                for (int j = 0; j < 8; ++j) {
                    const int tok = half * 8 + j;
                    float a = bias;
                    a = fmaf(dts[tok][0], dwv.x, a);
                    a = fmaf(dts[tok][1], dwv.y, a);
                    a = fmaf(dts[tok][2], dwv.z, a);
                    a = fmaf(dts[tok][3], dwv.w, a);
                    const float sp = fmaxf(a, 0.f) + log1pf(__expf(-fabsf(a)));
                    dl[tok][e] = sp;
                    if (store_dbc) P.dlt[(t0 + tok) * ED + e] = sp;
                }
            }
            __syncthreads();

            {   // local scan -> hsT LDS tile -> one coalesced sc1 stream
                float dsum = 0.f;
                #pragma unroll 4
                for (int l = 0; l < TT; ++l) dsum += dl[l][e];
                if (half == 0) stsc(&P.dsum[((size_t)b * NC + c) * ED + e], dsum);

                #pragma unroll 1
                for (int g = 0; g < 2; ++g) {
                    const int n0 = half * 16 + g * 8;
                    float Aen[8];
                    #pragma unroll
                    for (int k = 0; k < 8; ++k) Aen[k] = Aen16[g * 8 + k];
                    float hs[8];
                    #pragma unroll
                    for (int k = 0; k < 8; ++k) hs[k] = 0.f;
                    #pragma unroll 2
                    for (int l = 0; l < TT; ++l) {
                        const float de   = dl[l][e];
                        const float dexc = de * xcs[l][e];
                        const float4 B0 = *(const float4*)&Bs[l][n0];
                        const float4 B1 = *(const float4*)&Bs[l][n0 + 4];
                        float a;
                        a = EXP2F(de * Aen[0]); hs[0] = fmaf(a, hs[0], B0.x * dexc);
                        a = EXP2F(de * Aen[1]); hs[1] = fmaf(a, hs[1], B0.y * dexc);
                        a = EXP2F(de * Aen[2]); hs[2] = fmaf(a, hs[2], B0.z * dexc);
                        a = EXP2F(de * Aen[3]); hs[3] = fmaf(a, hs[3], B0.w * dexc);
                        a = EXP2F(de * Aen[4]); hs[4] = fmaf(a, hs[4], B1.x * dexc);
                        a = EXP2F(de * Aen[5]); hs[5] = fmaf(a, hs[5], B1.y * dexc);
                        a = EXP2F(de * Aen[6]); hs[6] = fmaf(a, hs[6], B1.z * dexc);
                        a = EXP2F(de * Aen[7]); hs[7] = fmaf(a, hs[7], B1.w * dexc);
                    }
                    #pragma unroll
                    for (int k = 0; k < 8; ++k) hsT[e * 33 + n0 + k] = hs[k];
                }
                __syncthreads();
                {
                    unsigned long long* dst =
                        (unsigned long long*)(P.hloc + (size_t)bid * (ED * NST));
                    #pragma unroll
                    for (int it = 0; it < 8; ++it) {
                        const int idx = tid + it * 256;    // u64 index, 0..2047
                        const int ee = idx >> 4;
                        const int nn = (idx & 15) * 2;
                        union { float f[2]; unsigned long long u; } pk;
                        pk.f[0] = hsT[ee * 33 + nn];
                        pk.f[1] = hsT[ee * 33 + nn + 1];
                        stsc64(dst + idx, pk.u);
                    }
                }
            }
        }
        bbar(cA, (unsigned)(li + 1) * 128u);   // per-batch: A(li) done for all c

        // ============ B: chunk combine (8-way segment-parallel) ============
        {
            const int tt  = tid & 31;
            const int seg = tid >> 5;
            const int t   = bid * 32 + tt;
            const int b   = t >> 12;
            const int en  = t & 4095;
            const int e   = en >> 5;

            const float Aen2 = -__expf(Alog[en]) * L2E;

            const int c0 = seg * (NC / NSEG);
            const size_t idxBase = (size_t)b * NC * (ED * NST) + en;
            const size_t dBase   = (size_t)b * NC * ED + e;

            float u[NC / NSEG], a[NC / NSEG];
            #pragma unroll
            for (int k = 0; k < NC / NSEG; ++k)
                u[k] = ldsc(P.hloc + idxBase + (size_t)(c0 + k) * (ED * NST));
            #pragma unroll
            for (int k = 0; k < NC / NSEG; ++k)
                a[k] = EXP2F(Aen2 * ldsc(P.dsum + dBase + (size_t)(c0 + k) * ED));

            float A = 1.f, U = 0.f;
            #pragma unroll
            for (int k = 0; k < NC / NSEG; ++k) { U = fmaf(a[k], U, u[k]); A *= a[k]; }

            float (*As)[32] = (float (*)[32])smem;
            float (*Us)[32] = (float (*)[32])(smem + NSEG * 32);
            As[seg][tt] = A; Us[seg][tt] = U;
            __syncthreads();

            float h = 0.f;
            #pragma unroll
            for (int j = 0; j < NSEG - 1; ++j)
                if (j < seg) h = fmaf(As[j][tt], h, Us[j][tt]);

            #pragma unroll
            for (int k = 0; k < NC / NSEG; ++k) {
                stsc(P.hloc + idxBase + (size_t)(c0 + k) * (ED * NST), h); // lane-contig
                h = fmaf(a[k], h, u[k]);
            }

            if (last && seg == NSEG - 1) {
                const int n = en & 31;
                const size_t tok = (size_t)b * Lseq + (Lseq - 1);
                float p = h * ldsc(P.Cv + tok * NST + n);
                #pragma unroll
                for (int off = 16; off; off >>= 1) p += __shfl_xor(p, off, 32);
                if (n == 0) {
                    const float xce = ldsc(P.xc + tok * ED + e);
                    const float zi  = ldsc(P.zbH + (size_t)b * ED + e);
                    float val = (p + Dpl[e] * xce) * (zi * sigf(zi)) * P.fc_w[e];
                    if (en == 0) val += P.fc_b[0];
                    atomicAdd(&P.out[b], val);
                }
            }
        }

        if (!last) {
            bbar(cB, (unsigned)(li + 1) * 128u);   // per-batch: B(li) done
            // ===== C: scan(y) + gate + outproj + residual + rms + inproj =====
            {
                const int b = bb, c = cc;
                const int l0 = c * TT;
                const size_t t0 = (size_t)b * Lseq + l0;
                const int e = tid & 127, half = tid >> 7;

                float (*dlS)[ED] = (float (*)[ED])(smem);
                float (*xcS)[ED] = (float (*)[ED])(smem + 2048);
                float (*BsS)[NST] = (float (*)[NST])(smem + 4096);
                float (*CsS)[NST] = (float (*)[NST])(smem + 4608);
                float (*ys)[ED]  = (float (*)[ED])(smem + 5120);
                float (*pp)[TT][ED] = (float (*)[TT][ED])(smem + 7168);
                float (*hn)[DM]  = (float (*)[DM])(smem + 11264);

                const float* ow = P.outproj_w + (size_t)li * DM * ED;
                const float* ob = P.outproj_b + (size_t)li * DM;
                const float* hres = (li == 0) ? P.x : ((li == 1) ? P.h0 : P.h1);
                float* hout = (li & 1) ? P.h1 : P.h0;

                float Aen16[16];
                {
                    const float4* a4 = (const float4*)(Alog + e * NST + half * 16);
                    #pragma unroll
                    for (int i = 0; i < 4; ++i) {
                        float4 v = a4[i];
                        Aen16[i*4+0] = -__expf(v.x) * L2E; Aen16[i*4+1] = -__expf(v.y) * L2E;
                        Aen16[i*4+2] = -__expf(v.z) * L2E; Aen16[i*4+3] = -__expf(v.w) * L2E;
                    }
                }

                // hinit: cross-block (combine wrote it) -> one contiguous 64-B
                // sc1 read per thread (full sector utilization)
                float hs16[16];
                {
                    const size_t idx = (size_t)bid * (ED * NST) + e * NST + half * 16;
                    const unsigned long long* src =
                        (const unsigned long long*)(P.hloc + idx);
                    #pragma unroll
                    for (int k = 0; k < 8; ++k) {
                        union { float f[2]; unsigned long long u; } pk;
                        pk.u = ldsc64(src + k);
                        hs16[2 * k]     = pk.f[0];
                        hs16[2 * k + 1] = pk.f[1];
                    }
                }

                {   // dlt/xc/Bv/Cv: same-block plain (L2-hot)
                    const float4* dsrc = (const float4*)(P.dlt + t0 * ED);
                    const float4* xsrc = (const float4*)(P.xc + t0 * ED);
                    float4* ddst = (float4*)&dlS[0][0];
                    float4* xdst = (float4*)&xcS[0][0];
                    #pragma unroll
                    for (int i = 0; i < 2; ++i) {
                        ddst[tid + i * 256] = dsrc[tid + i * 256];
                        xdst[tid + i * 256] = xsrc[tid + i * 256];
                    }
                    if (tid < 128) {
                        ((float4*)&BsS[0][0])[tid] = ((const float4*)(P.Bv + t0 * NST))[tid];
                        ((float4*)&CsS[0][0])[tid] = ((const float4*)(P.Cv + t0 * NST))[tid];
                    }
                }
                __syncthreads();

                #pragma unroll 1
                for (int g = 0; g < 2; ++g) {
                    const int n0 = half * 16 + g * 8;
                    float Aen[8];
                    #pragma unroll
                    for (int k = 0; k < 8; ++k) Aen[k] = Aen16[g * 8 + k];
                    float hs[8];
                    #pragma unroll
                    for (int k = 0; k < 8; ++k) hs[k] = hs16[g * 8 + k];
                    #pragma unroll 2
                    for (int l = 0; l < TT; ++l) {
                        const float de   = dlS[l][e];
                        const float dexc = de * xcS[l][e];
                        const float4 B0 = *(const float4*)&BsS[l][n0];
                        const float4 B1 = *(const float4*)&BsS[l][n0 + 4];
                        const float4 C0 = *(const float4*)&CsS[l][n0];
                        const float4 C1 = *(const float4*)&CsS[l][n0 + 4];
                        float a, p = 0.f;
                        a = EXP2F(de * Aen[0]); hs[0] = fmaf(a, hs[0], B0.x * dexc); p = fmaf(hs[0], C0.x, p);
                        a = EXP2F(de * Aen[1]); hs[1] = fmaf(a, hs[1], B0.y * dexc); p = fmaf(hs[1], C0.y, p);
                        a = EXP2F(de * Aen[2]); hs[2] = fmaf(a, hs[2], B0.z * dexc); p = fmaf(hs[2], C0.z, p);
                        a = EXP2F(de * Aen[3]); hs[3] = fmaf(a, hs[3], B0.w * dexc); p = fmaf(hs[3], C0.w, p);
                        a = EXP2F(de * Aen[4]); hs[4] = fmaf(a, hs[4], B1.x * dexc); p = fmaf(hs[4], C1.x, p);
                        a = EXP2F(de * Aen[5]); hs[5] = fmaf(a, hs[5], B1.y * dexc); p = fmaf(hs[5], C1.y, p);
                        a = EXP2F(de * Aen[6]); hs[6] = fmaf(a, hs[6], B1.z * dexc); p = fmaf(hs[6], C1.z, p);
                        a = EXP2F(de * Aen[7]); hs[7] = fmaf(a, hs[7], B1.w * dexc); p = fmaf(hs[7], C1.w, p);
                        if (g == 0) pp[half][l][e] = p;
                        else        pp[half][l][e] += p;
                    }
                }
                __syncthreads();
                {
                    const float dpe = Dpl[e];
                    #pragma unroll 2
                    for (int j = 0; j < 8; ++j) {
                        const int tl = half * 8 + j;
                        const size_t tok = t0 + tl;
                        const float p = pp[0][tl][e] + pp[1][tl][e];
                        const float zi = P.zbuf[tok * ED + e];   // same-block plain
                        ys[tl][e] = (p + dpe * xcS[tl][e]) * (zi * sigf(zi));
                    }
                }
                __syncthreads();

                const int lane = tid & 63;
                const int wv = tid >> 6;
                const float nw = P.norm_w[(size_t)(li + 1) * DM + lane];
                float hval[4];
                {
                    float4 acc[4];
                    #pragma unroll
                    for (int j = 0; j < 4; ++j) acc[j] = make_float4(0.f, 0.f, 0.f, 0.f);
                    #pragma unroll 1
                    for (int p = 0; p < 4; ++p) {
                        float4 w4[8];
                        const float4* wr = (const float4*)(ow + lane * ED + p * 32);
                        #pragma unroll
                        for (int q = 0; q < 8; ++q) w4[q] = wr[q];
                        #pragma unroll
                        for (int j = 0; j < 4; ++j) {
                            const float4* yv = (const float4*)&ys[wv * 4 + j][p * 32];
                            #pragma unroll
                            for (int q = 0; q < 8; ++q) {
                                float4 hv = yv[q];
                                acc[j].x = fmaf(hv.x, w4[q].x, acc[j].x);
                                acc[j].y = fmaf(hv.y, w4[q].y, acc[j].y);
                                acc[j].z = fmaf(hv.z, w4[q].z, acc[j].z);
                                acc[j].w = fmaf(hv.w, w4[q].w, acc[j].w);
                            }
                        }
                    }
                    const float obd = ob[lane];
                    #pragma unroll
                    for (int j = 0; j < 4; ++j) {
                        const size_t tok = t0 + wv * 4 + j;
                        hval[j] = hsum4(acc[j]) + obd + hres[tok * DM + lane];
                        hout[tok * DM + lane] = hval[j];   // same-block consumer
                    }
                }
                #pragma unroll
                for (int j = 0; j < 4; ++j) {
                    float ss = hval[j] * hval[j];
                    #pragma unroll
                    for (int off = 32; off; off >>= 1) ss += __shfl_xor(ss, off, 64);
                    const float sc = rsqrtf(ss * (1.0f / DM) + EPSV);
                    hn[wv * 4 + j][lane] = hval[j] * sc * nw;
                }
                __syncthreads();
                inproj16(P.in_w + (size_t)(li + 1) * 2 * ED * DM,
                         P.in_b + (size_t)(li + 1) * 2 * ED,
                         (const float (*)[DM])hn, P.xin, P.zbuf,
                         haloW, zbH_b, lastChunk, t0, tid);
            }
            __syncthreads();   // drain halo stores, then publish epoch li+2
            if (tid == 0)
                __hip_atomic_store(&P.hflag[bid * 16], (unsigned)(li + 2),
                                   __ATOMIC_RELAXED, __HIP_MEMORY_SCOPE_AGENT);
        }
    }
}

extern "C" void kernel_launch(void* const* d_in, const int* in_sizes, int n_in,
                              void* d_out, int out_size, void* d_ws, size_t ws_size,
                              hipStream_t stream)
{
    const size_t TOK = (size_t)BSZ * Lseq;
    float* ws = (float*)d_ws;
    float* h0    = ws; ws += TOK * DM;
    float* h1    = ws; ws += TOK * DM;
    float* xin   = ws; ws += TOK * ED;
    float* zbuf  = ws; ws += TOK * ED;
    float* xc    = ws; ws += TOK * ED;
    float* dlt   = ws; ws += TOK * ED;
    float* Bv    = ws; ws += TOK * NST;
    float* Cv    = ws; ws += TOK * NST;
    float* dsum  = ws; ws += (size_t)BSZ * NC * ED;               // 256 KB
    float* hloc  = ws; ws += (size_t)BSZ * NC * ED * NST;         // 8 MB
    float* H     = ws; ws += (size_t)GRIDN * (DCONVK - 1) * ED;   // 3.9 MB halo
    float* zbH   = ws; ws += (size_t)BSZ * ED;                    // head z copy
    unsigned int* cntA  = (unsigned int*)ws;                       // 4 padded counters
    unsigned int* cntB  = cntA + BSZ * 64;                         // 4 padded counters
    unsigned int* hflag = cntB + BSZ * 64;                         // 512 padded flags

    KParams prm;
    prm.x         = (const float*)d_in[0];
    prm.in_w      = (const float*)d_in[1];
    prm.in_b      = (const float*)d_in[2];
    prm.conv_w    = (const float*)d_in[3];
    prm.conv_b    = (const float*)d_in[4];
    prm.xproj_w   = (const float*)d_in[5];
    prm.dtproj_w  = (const float*)d_in[6];
    prm.dtproj_b  = (const float*)d_in[7];
    prm.A_log     = (const float*)d_in[8];
    prm.Dp        = (const float*)d_in[9];
    prm.outproj_w = (const float*)d_in[10];
    prm.outproj_b = (const float*)d_in[11];
    prm.norm_w    = (const float*)d_in[12];
    prm.fc_w      = (const float*)d_in[13];
    prm.fc_b      = (const float*)d_in[14];
    prm.out  = (float*)d_out;
    prm.h0 = h0; prm.h1 = h1; prm.xin = xin; prm.zbuf = zbuf;
    prm.xc = xc; prm.dlt = dlt; prm.Bv = Bv; prm.Cv = Cv;
    prm.dsum = dsum; prm.hloc = hloc; prm.H = H; prm.zbH = zbH;
    prm.cntA = cntA; prm.cntB = cntB; prm.hflag = hflag;

    // zero output (atomicAdd target; per-iteration under graph replay) and
    // all sync counters/flags — both graph-capturable
    hipMemsetAsync(d_out, 0, (size_t)BSZ * sizeof(float), stream);
    hipMemsetAsync(cntA, 0, (size_t)(2 * BSZ * 64 + 512 * 16) * sizeof(unsigned int),
                   stream);
    k_mamba<<<dim3(GRIDN), dim3(256), 0, stream>>>(prm);
}

// Round 9
// 310.432 us; speedup vs baseline: 1.2761x; 1.2761x over previous
//
#include <hip/hip_runtime.h>
#include <math.h>

#define BSZ 4
#define Lseq 2048
#define DM 64
#define ED 128
#define NST 32
#define DCONVK 16
#define NLAYERS 4
#define DTRANK 4
#define EPSV 1e-5f
#define NC 128                // chunks along L (chunk == conv tile == gemm tile)
#define TT 16                 // tokens per block
#define NSEG 8                // combine: segments per (b,e,n) scan
#define L2E 1.4426950408889634f

#if defined(__has_builtin)
#if __has_builtin(__builtin_amdgcn_exp2f)
#define EXP2F(x) __builtin_amdgcn_exp2f(x)
#else
#define EXP2F(x) exp2f(x)
#endif
#else
#define EXP2F(x) exp2f(x)
#endif

__device__ __forceinline__ float sigf(float x) { return 1.0f / (1.0f + __expf(-x)); }
__device__ __forceinline__ float hsum4(float4 a) { return (a.x + a.y) + (a.z + a.w); }

// Chunked XCD swizzle (bijective on 512): HW assigns XCD = blockIdx % 8;
// remap so each XCD owns 64 CONSECUTIVE logical chunks (one batch spans an
// XCD pair). Effects: (a) conv-halo producer (chunk c-1) and consumer (c)
// share an XCD 63/64 of the time -> post-dispatch L2 hits; (b) same-chunk
// data re-read across dispatches (xc/dlt/Bv/Cv) keeps XCD affinity because
// every per-chunk kernel uses the same map. Addresses unchanged -> safe.
__device__ __forceinline__ int swz(int bid) {
    return (bid & 7) * 64 + (bid >> 3);
}

// inproj: 64 -> 256 for 16 tokens; hn in LDS; writes xin (tid<128) / zbuf.
__device__ __forceinline__ void inproj16(
    const float* in_w_l, const float* in_b_l, const float (*hn)[DM],
    float* xin, float* zbuf, size_t t0, int tid)
{
    float4 w4[16];
    const float4* wr = (const float4*)(in_w_l + tid * DM);
    #pragma unroll
    for (int i = 0; i < 16; ++i) w4[i] = wr[i];
    const float bias = in_b_l[tid];
    #pragma unroll 2
    for (int tok = 0; tok < TT; ++tok) {
        const float4* hv4 = (const float4*)&hn[tok][0];
        float4 a4 = make_float4(0.f, 0.f, 0.f, 0.f);
        #pragma unroll
        for (int i = 0; i < 16; ++i) {
            float4 hv = hv4[i];
            a4.x = fmaf(hv.x, w4[i].x, a4.x);
            a4.y = fmaf(hv.y, w4[i].y, a4.y);
            a4.z = fmaf(hv.z, w4[i].z, a4.z);
            a4.w = fmaf(hv.w, w4[i].w, a4.w);
        }
        const float r = bias + hsum4(a4);
        if (tid < ED) xin[(t0 + tok) * ED + tid] = r;
        else          zbuf[(t0 + tok) * ED + (tid - ED)] = r;
    }
}

// ---------------- K_A (layer 0 only): rmsnorm + inproj, 16 tokens/block
__global__ __launch_bounds__(256) void k_layer_gemm(
    const float* __restrict__ hin, const float* __restrict__ norm_w,
    const float* __restrict__ in_w, const float* __restrict__ in_b,
    float* __restrict__ xin, float* __restrict__ zb, float* __restrict__ out)
{
    const int t0 = swz(blockIdx.x) * TT;
    const int tid = threadIdx.x;
    const int lane = tid & 63;
    const int wv = tid >> 6;
    __shared__ __align__(16) float hn[TT][DM];

    if (blockIdx.x == 0 && tid < BSZ) out[tid] = 0.f;

    const float nw = norm_w[lane];
    float hval[4];
    #pragma unroll
    for (int j = 0; j < 4; ++j)
        hval[j] = hin[(size_t)(t0 + wv * 4 + j) * DM + lane];

    #pragma unroll
    for (int j = 0; j < 4; ++j) {
        float ss = hval[j] * hval[j];
        #pragma unroll
        for (int off = 32; off; off >>= 1) ss += __shfl_xor(ss, off, 64);
        const float sc = rsqrtf(ss * (1.0f / DM) + EPSV);
        hn[wv * 4 + j][lane] = hval[j] * sc * nw;
    }
    __syncthreads();
    inproj16(in_w, in_b, (const float (*)[DM])hn, xin, zb, (size_t)t0, tid);
}

// ---------------- K_B: conv + silu + xproj + dtproj + local scan — 1 chunk/block
__global__ __launch_bounds__(256) void k_conv_scan(
    const float* __restrict__ xin, const float* __restrict__ conv_w,
    const float* __restrict__ conv_b, const float* __restrict__ xproj_w,
    const float* __restrict__ dtproj_w, const float* __restrict__ dtproj_b,
    const float* __restrict__ A_log,
    float* __restrict__ xc_out, float* __restrict__ delta_out,
    float* __restrict__ Bout, float* __restrict__ Cout,
    float* __restrict__ dsum_out, float* __restrict__ hloc, int store_dbc)
{
    const int blk = swz(blockIdx.x);        // logical chunk id (XCD-chunked)
    const int b   = blk >> 7;               // NC = 128
    const int c   = blk & 127;
    const int l0  = c * TT;
    const size_t t0 = (size_t)b * Lseq + l0;
    const int tid = threadIdx.x;
    const int e = tid & 127, half = tid >> 7;
    const bool doXC = store_dbc || (c == NC - 1);
    __shared__ __align__(16) float xs[(TT + DCONVK - 1) * ED];   // 31 rows, 15.5 KB
    __shared__ __align__(16) float xcs[TT][ED];                   // 8 KB
    __shared__ __align__(16) float Bs[TT][NST];                   // 2 KB
    __shared__ float dts[TT][DTRANK];
    float (*dl)[ED] = (float (*)[ED])xs;    // alias: xs dead after conv phase

    // hoisted loads; Aen pre-scaled by log2(e) for hardware exp2
    float Aen16[16];
    {
        const float4* a4 = (const float4*)(A_log + e * NST + half * 16);
        #pragma unroll
        for (int i = 0; i < 4; ++i) {
            float4 v = a4[i];
            Aen16[i*4+0] = -__expf(v.x) * L2E; Aen16[i*4+1] = -__expf(v.y) * L2E;
            Aen16[i*4+2] = -__expf(v.z) * L2E; Aen16[i*4+3] = -__expf(v.w) * L2E;
        }
    }
    float w[DCONVK];
    {
        const float4* cw = (const float4*)(conv_w + e * DCONVK);
        #pragma unroll
        for (int i = 0; i < 4; ++i) {
            float4 cc = cw[i];
            w[i*4+0] = cc.x; w[i*4+1] = cc.y; w[i*4+2] = cc.z; w[i*4+3] = cc.w;
        }
    }
    const float cb = conv_b[e];

    {
        const int NV = (TT + DCONVK - 1) * ED / 4;   // 992
        for (int idx4 = tid; idx4 < NV; idx4 += 256) {
            const int row = idx4 >> 5;
            const int lrow = l0 - (DCONVK - 1) + row;
            float4 v = make_float4(0.f, 0.f, 0.f, 0.f);
            if (lrow >= 0)
                v = ((const float4*)(xin + ((size_t)b * Lseq + lrow) * ED))[idx4 & 31];
            ((float4*)xs)[idx4] = v;
        }
    }
    __syncthreads();

    {   // conv + silu
        #pragma unroll 2
        for (int j = 0; j < 8; ++j) {
            const int tok = half * 8 + j;
            float acc = cb;
            #pragma unroll
            for (int k = 0; k < DCONVK; ++k)
                acc = fmaf(xs[(tok + k) * ED + e], w[k], acc);
            const float xcv = acc * sigf(acc);
            xcs[tok][e] = xcv;
            if (doXC) xc_out[(t0 + tok) * ED + e] = xcv;
        }
    }
    __syncthreads();   // xs dead from here on

    {   // xproj: 4 passes of w4[8], acc[4]
        const int wv = tid >> 6, lane = tid & 63;
        float4 acc[4];
        #pragma unroll
        for (int j = 0; j < 4; ++j) acc[j] = make_float4(0.f, 0.f, 0.f, 0.f);
        #pragma unroll 1
        for (int p = 0; p < 4; ++p) {
            float4 w4[8];
            const float4* wr = (const float4*)(xproj_w + lane * ED + p * 32);
            #pragma unroll
            for (int i = 0; i < 8; ++i) w4[i] = wr[i];
            #pragma unroll
            for (int j = 0; j < 4; ++j) {
                const float4* yv = (const float4*)&xcs[wv * 4 + j][p * 32];
                #pragma unroll
                for (int i = 0; i < 8; ++i) {
                    float4 hv = yv[i];
                    acc[j].x = fmaf(hv.x, w4[i].x, acc[j].x);
                    acc[j].y = fmaf(hv.y, w4[i].y, acc[j].y);
                    acc[j].z = fmaf(hv.z, w4[i].z, acc[j].z);
                    acc[j].w = fmaf(hv.w, w4[i].w, acc[j].w);
                }
            }
        }
        #pragma unroll
        for (int j = 0; j < 4; ++j) {
            const int tok = wv * 4 + j;
            const float v = hsum4(acc[j]);
            if (lane < DTRANK) {
                dts[tok][lane] = v;
            } else if (lane < DTRANK + NST) {
                Bs[tok][lane - DTRANK] = v;
                if (store_dbc) Bout[(t0 + tok) * NST + (lane - DTRANK)] = v;
            } else {
                if (doXC) Cout[(t0 + tok) * NST + (lane - DTRANK - NST)] = v;
            }
        }
        {
            const int ridx = lane & 3;
            const int ks   = (lane >> 2) & 3;
            const int tsub = lane >> 4;
            const int r4   = 64 + ridx;
            const int tok  = wv * 4 + tsub;
            const float4* wr = (const float4*)(xproj_w + r4 * ED + ks * 32);
            const float4* yv = (const float4*)&xcs[tok][ks * 32];
            float4 a4 = make_float4(0.f, 0.f, 0.f, 0.f);
            #pragma unroll
            for (int i = 0; i < 8; ++i) {
                float4 hv = yv[i]; float4 wv4 = wr[i];
                a4.x = fmaf(hv.x, wv4.x, a4.x);
                a4.y = fmaf(hv.y, wv4.y, a4.y);
                a4.z = fmaf(hv.z, wv4.z, a4.z);
                a4.w = fmaf(hv.w, wv4.w, a4.w);
            }
            float v = hsum4(a4);
            v += __shfl_xor(v, 4, 64);
            v += __shfl_xor(v, 8, 64);
            if (ks == 0 && doXC) Cout[(t0 + tok) * NST + (r4 - DTRANK - NST)] = v;
        }
    }
    __syncthreads();

    {   // dtproj + softplus -> dl (aliased LDS) + delta_out
        const float4 dwv = *(const float4*)(dtproj_w + e * DTRANK);
        const float bias = dtproj_b[e];
        #pragma unroll 2
        for (int j = 0; j < 8; ++j) {
            const int tok = half * 8 + j;
            float a = bias;
            a = fmaf(dts[tok][0], dwv.x, a);
            a = fmaf(dts[tok][1], dwv.y, a);
            a = fmaf(dts[tok][2], dwv.z, a);
            a = fmaf(dts[tok][3], dwv.w, a);
            const float sp = fmaxf(a, 0.f) + log1pf(__expf(-fabsf(a)));
            dl[tok][e] = sp;
            if (store_dbc) delta_out[(t0 + tok) * ED + e] = sp;
        }
    }
    __syncthreads();

    {   // local scan: two 8-state passes, hardware exp2
        float dsum = 0.f;
        #pragma unroll 4
        for (int l = 0; l < TT; ++l) dsum += dl[l][e];
        if (half == 0) dsum_out[((size_t)b * NC + c) * ED + e] = dsum;

        #pragma unroll 1
        for (int g = 0; g < 2; ++g) {
            const int n0 = half * 16 + g * 8;
            float Aen[8];
            #pragma unroll
            for (int k = 0; k < 8; ++k) Aen[k] = Aen16[g * 8 + k];
            float hs[8];
            #pragma unroll
            for (int k = 0; k < 8; ++k) hs[k] = 0.f;
            #pragma unroll 2
            for (int l = 0; l < TT; ++l) {
                const float de   = dl[l][e];
                const float dexc = de * xcs[l][e];
                const float4 B0 = *(const float4*)&Bs[l][n0];
                const float4 B1 = *(const float4*)&Bs[l][n0 + 4];
                float a;
                a = EXP2F(de * Aen[0]); hs[0] = fmaf(a, hs[0], B0.x * dexc);
                a = EXP2F(de * Aen[1]); hs[1] = fmaf(a, hs[1], B0.y * dexc);
                a = EXP2F(de * Aen[2]); hs[2] = fmaf(a, hs[2], B0.z * dexc);
                a = EXP2F(de * Aen[3]); hs[3] = fmaf(a, hs[3], B0.w * dexc);
                a = EXP2F(de * Aen[4]); hs[4] = fmaf(a, hs[4], B1.x * dexc);
                a = EXP2F(de * Aen[5]); hs[5] = fmaf(a, hs[5], B1.y * dexc);
                a = EXP2F(de * Aen[6]); hs[6] = fmaf(a, hs[6], B1.z * dexc);
                a = EXP2F(de * Aen[7]); hs[7] = fmaf(a, hs[7], B1.w * dexc);
            }
            const size_t idx = (((size_t)b * NC + c) * ED + e) * NST + n0;
            *(float4*)(hloc + idx)     = make_float4(hs[0], hs[1], hs[2], hs[3]);
            *(float4*)(hloc + idx + 4) = make_float4(hs[4], hs[5], hs[6], hs[7]);
        }
    }
}

// ---------------- K3b: chunk combine, 8-way segment-parallel (512x256).
// final==1: skip the exclusive-prefix writes (dead stores — no scan_gemm
// follows the last layer; saves 8 MB) and run the fused classifier head.
__global__ __launch_bounds__(256) void k_scan_combine(
    const float* __restrict__ dsum, float* __restrict__ hloc,
    const float* __restrict__ A_log,
    const float* __restrict__ Cv, const float* __restrict__ xc,
    const float* __restrict__ zb, const float* __restrict__ Dp,
    const float* __restrict__ fcw, const float* __restrict__ fcb,
    float* __restrict__ out, int final)
{
    const int tid = threadIdx.x;
    const int tt  = tid & 31;                 // tuple within block
    const int seg = tid >> 5;                 // 0..7
    const int t   = blockIdx.x * 32 + tt;     // 0..16383  (b,e,n) tuple
    const int b   = t >> 12;                  // ED*NST = 4096
    const int en  = t & 4095;
    const int e   = en >> 5;

    const float Aen2 = -__expf(A_log[en]) * L2E;

    const int c0 = seg * (NC / NSEG);         // 16 chunks per segment
    const size_t idxBase = (size_t)b * NC * (ED * NST) + en;
    const size_t dBase   = (size_t)b * NC * ED + e;

    float u[NC / NSEG], a[NC / NSEG];
    #pragma unroll
    for (int k = 0; k < NC / NSEG; ++k)
        u[k] = hloc[idxBase + (size_t)(c0 + k) * (ED * NST)];
    #pragma unroll
    for (int k = 0; k < NC / NSEG; ++k)
        a[k] = EXP2F(Aen2 * dsum[dBase + (size_t)(c0 + k) * ED]);

    float A = 1.f, U = 0.f;                   // segment affine map: x -> A*x + U
    #pragma unroll
    for (int k = 0; k < NC / NSEG; ++k) { U = fmaf(a[k], U, u[k]); A *= a[k]; }

    __shared__ float As[NSEG][32], Us[NSEG][32];
    As[seg][tt] = A; Us[seg][tt] = U;
    __syncthreads();

    float h = 0.f;                            // exclusive prefix over segments
    #pragma unroll
    for (int j = 0; j < NSEG - 1; ++j)
        if (j < seg) h = fmaf(As[j][tt], h, Us[j][tt]);

    if (final) {
        if (seg == NSEG - 1) {
            #pragma unroll
            for (int k = 0; k < NC / NSEG; ++k) h = fmaf(a[k], h, u[k]);
            const int n = en & 31;
            const size_t tok = (size_t)b * Lseq + (Lseq - 1);
            float p = h * Cv[tok * NST + n];
            #pragma unroll
            for (int off = 16; off; off >>= 1) p += __shfl_xor(p, off, 32);
            if (n == 0) {
                const float xce = xc[tok * ED + e];
                const float zi  = zb[tok * ED + e];
                float val = (p + Dp[e] * xce) * (zi * sigf(zi)) * fcw[e];
                if (en == 0) val += fcb[0];
                atomicAdd(&out[b], val);
            }
        }
    } else {
        #pragma unroll
        for (int k = 0; k < NC / NSEG; ++k) {
            hloc[idxBase + (size_t)(c0 + k) * (ED * NST)] = h;   // initial state
            h = fmaf(a[k], h, u[k]);
        }
    }
}

// ---------------- K_C (layers 1..3): scan(y) + outproj + residual + rms + inproj
__global__ __launch_bounds__(256) void k_scan_gemm(
    const float* __restrict__ delta, const float* __restrict__ Bv,
    const float* __restrict__ Cv, const float* __restrict__ xc,
    const float* __restrict__ zbin, const float* __restrict__ A_log,
    const float* __restrict__ Dp, const float* __restrict__ hinit,
    const float* __restrict__ ow, const float* __restrict__ ob,
    const float* __restrict__ hin, const float* __restrict__ norm_w,
    const float* __restrict__ in_w, const float* __restrict__ in_b,
    float* __restrict__ hout, float* __restrict__ xin, float* __restrict__ zb)
{
    const int blk = swz(blockIdx.x);        // logical chunk id (XCD-chunked)
    const int b   = blk >> 7;
    const int c   = blk & 127;
    const int l0  = c * TT;
    const size_t t0 = (size_t)b * Lseq + l0;
    const int tid = threadIdx.x;
    const int e = tid & 127, half = tid >> 7;

    __shared__ __align__(16) float dlS[TT][ED];
    __shared__ __align__(16) float xcS[TT][ED];
    __shared__ __align__(16) float BsS[TT][NST];
    __shared__ __align__(16) float CsS[TT][NST];
    __shared__ __align__(16) float ys[TT][ED];
    __shared__ __align__(16) float pp[2][TT][ED];
    __shared__ __align__(16) float hn[TT][DM];

    float Aen16[16];
    {
        const float4* a4 = (const float4*)(A_log + e * NST + half * 16);
        #pragma unroll
        for (int i = 0; i < 4; ++i) {
            float4 v = a4[i];
            Aen16[i*4+0] = -__expf(v.x) * L2E; Aen16[i*4+1] = -__expf(v.y) * L2E;
            Aen16[i*4+2] = -__expf(v.z) * L2E; Aen16[i*4+3] = -__expf(v.w) * L2E;
        }
    }

    {
        const float4* dsrc = (const float4*)(delta + t0 * ED);
        const float4* xsrc = (const float4*)(xc + t0 * ED);
        float4* ddst = (float4*)&dlS[0][0];
        float4* xdst = (float4*)&xcS[0][0];
        #pragma unroll
        for (int i = 0; i < 2; ++i) {
            ddst[tid + i * 256] = dsrc[tid + i * 256];
            xdst[tid + i * 256] = xsrc[tid + i * 256];
        }
        if (tid < 128) {
            ((float4*)&BsS[0][0])[tid] = ((const float4*)(Bv + t0 * NST))[tid];
            ((float4*)&CsS[0][0])[tid] = ((const float4*)(Cv + t0 * NST))[tid];
        }
    }
    __syncthreads();

    #pragma unroll 1
    for (int g = 0; g < 2; ++g) {
        const int n0 = half * 16 + g * 8;
        float Aen[8];
        #pragma unroll
        for (int k = 0; k < 8; ++k) Aen[k] = Aen16[g * 8 + k];
        float hs[8];
        {
            const size_t idx = (((size_t)b * NC + c) * ED + e) * NST + n0;
            const float4 h0 = *(const float4*)(hinit + idx);
            const float4 h1 = *(const float4*)(hinit + idx + 4);
            hs[0] = h0.x; hs[1] = h0.y; hs[2] = h0.z; hs[3] = h0.w;
            hs[4] = h1.x; hs[5] = h1.y; hs[6] = h1.z; hs[7] = h1.w;
        }
        #pragma unroll 2
        for (int l = 0; l < TT; ++l) {
            const float de   = dlS[l][e];
            const float dexc = de * xcS[l][e];
            const float4 B0 = *(const float4*)&BsS[l][n0];
            const float4 B1 = *(const float4*)&BsS[l][n0 + 4];
            const float4 C0 = *(const float4*)&CsS[l][n0];
            const float4 C1 = *(const float4*)&CsS[l][n0 + 4];
            float a, p = 0.f;
            a = EXP2F(de * Aen[0]); hs[0] = fmaf(a, hs[0], B0.x * dexc); p = fmaf(hs[0], C0.x, p);
            a = EXP2F(de * Aen[1]); hs[1] = fmaf(a, hs[1], B0.y * dexc); p = fmaf(hs[1], C0.y, p);
            a = EXP2F(de * Aen[2]); hs[2] = fmaf(a, hs[2], B0.z * dexc); p = fmaf(hs[2], C0.z, p);
            a = EXP2F(de * Aen[3]); hs[3] = fmaf(a, hs[3], B0.w * dexc); p = fmaf(hs[3], C0.w, p);
            a = EXP2F(de * Aen[4]); hs[4] = fmaf(a, hs[4], B1.x * dexc); p = fmaf(hs[4], C1.x, p);
            a = EXP2F(de * Aen[5]); hs[5] = fmaf(a, hs[5], B1.y * dexc); p = fmaf(hs[5], C1.y, p);
            a = EXP2F(de * Aen[6]); hs[6] = fmaf(a, hs[6], B1.z * dexc); p = fmaf(hs[6], C1.z, p);
            a = EXP2F(de * Aen[7]); hs[7] = fmaf(a, hs[7], B1.w * dexc); p = fmaf(hs[7], C1.w, p);
            if (g == 0) pp[half][l][e] = p;
            else        pp[half][l][e] += p;
        }
    }
    __syncthreads();
    {
        const float dpe = Dp[e];
        #pragma unroll 2
        for (int j = 0; j < 8; ++j) {
            const int tl = half * 8 + j;
            const size_t tok = t0 + tl;
            const float p = pp[0][tl][e] + pp[1][tl][e];
            const float zi = zbin[tok * ED + e];
            ys[tl][e] = (p + dpe * xcS[tl][e]) * (zi * sigf(zi));
        }
    }
    __syncthreads();

    const int lane = tid & 63;
    const int wv = tid >> 6;
    const float nw = norm_w[lane];
    float hval[4];
    {
        float4 acc[4];
        #pragma unroll
        for (int j = 0; j < 4; ++j) acc[j] = make_float4(0.f, 0.f, 0.f, 0.f);
        #pragma unroll 1
        for (int p = 0; p < 4; ++p) {
            float4 w4[8];
            const float4* wr = (const float4*)(ow + lane * ED + p * 32);
            #pragma unroll
            for (int q = 0; q < 8; ++q) w4[q] = wr[q];
            #pragma unroll
            for (int j = 0; j < 4; ++j) {
                const float4* yv = (const float4*)&ys[wv * 4 + j][p * 32];
                #pragma unroll
                for (int q = 0; q < 8; ++q) {
                    float4 hv = yv[q];
                    acc[j].x = fmaf(hv.x, w4[q].x, acc[j].x);
                    acc[j].y = fmaf(hv.y, w4[q].y, acc[j].y);
                    acc[j].z = fmaf(hv.z, w4[q].z, acc[j].z);
                    acc[j].w = fmaf(hv.w, w4[q].w, acc[j].w);
                }
            }
        }
        const float obd = ob[lane];
        #pragma unroll
        for (int j = 0; j < 4; ++j) {
            const size_t tok = t0 + wv * 4 + j;
            hval[j] = hsum4(acc[j]) + obd + hin[tok * DM + lane];
            hout[tok * DM + lane] = hval[j];
        }
    }
    #pragma unroll
    for (int j = 0; j < 4; ++j) {
        float ss = hval[j] * hval[j];
        #pragma unroll
        for (int off = 32; off; off >>= 1) ss += __shfl_xor(ss, off, 64);
        const float sc = rsqrtf(ss * (1.0f / DM) + EPSV);
        hn[wv * 4 + j][lane] = hval[j] * sc * nw;
    }
    __syncthreads();
    inproj16(in_w, in_b, (const float (*)[DM])hn, xin, zb, t0, tid);
}

extern "C" void kernel_launch(void* const* d_in, const int* in_sizes, int n_in,
                              void* d_out, int out_size, void* d_ws, size_t ws_size,
                              hipStream_t stream)
{
    const float* x         = (const float*)d_in[0];
    const float* in_w      = (const float*)d_in[1];
    const float* in_b      = (const float*)d_in[2];
    const float* conv_w    = (const float*)d_in[3];
    const float* conv_b    = (const float*)d_in[4];
    const float* xproj_w   = (const float*)d_in[5];
    const float* dtproj_w  = (const float*)d_in[6];
    const float* dtproj_b  = (const float*)d_in[7];
    const float* A_log     = (const float*)d_in[8];
    const float* Dp        = (const float*)d_in[9];
    const float* outproj_w = (const float*)d_in[10];
    const float* outproj_b = (const float*)d_in[11];
    const float* norm_w    = (const float*)d_in[12];
    const float* fc_w      = (const float*)d_in[13];
    const float* fc_b      = (const float*)d_in[14];

    const size_t TOK = (size_t)BSZ * Lseq;
    float* ws = (float*)d_ws;
    float* h0    = ws; ws += TOK * DM;
    float* h1    = ws; ws += TOK * DM;
    float* xin   = ws; ws += TOK * ED;
    float* zbuf  = ws; ws += TOK * ED;
    float* xc    = ws; ws += TOK * ED;
    float* dlt   = ws; ws += TOK * ED;
    float* Bv    = ws; ws += TOK * NST;
    float* Cv    = ws; ws += TOK * NST;
    float* dsum  = ws; ws += (size_t)BSZ * NC * ED;          // 256 KB
    float* hloc  = ws; ws += (size_t)BSZ * NC * ED * NST;    // 8 MB, becomes hinit

    const float* hres = x;
    float* hbufs[2] = { h0, h1 };

    k_layer_gemm<<<(int)(TOK / TT), 256, 0, stream>>>(
        x, norm_w, in_w, in_b, xin, zbuf, (float*)d_out);

    for (int i = 0; i < NLAYERS; ++i) {
        const int last = (i == NLAYERS - 1);
        const float* Alog_i = A_log + (size_t)i * ED * NST;
        k_conv_scan<<<(int)(BSZ * NC), 256, 0, stream>>>(
            xin, conv_w + (size_t)i * ED * DCONVK, conv_b + (size_t)i * ED,
            xproj_w + (size_t)i * (DTRANK + 2 * NST) * ED,
            dtproj_w + (size_t)i * ED * DTRANK, dtproj_b + (size_t)i * ED,
            Alog_i, xc, dlt, Bv, Cv, dsum, hloc, last ? 0 : 1);
        k_scan_combine<<<(BSZ * ED * NST * NSEG) / 256, 256, 0, stream>>>(
            dsum, hloc, Alog_i, Cv, xc, zbuf, Dp + (size_t)i * ED,
            fc_w, fc_b, (float*)d_out, last ? 1 : 0);
        if (!last) {
            float* hout = hbufs[i & 1];
            k_scan_gemm<<<(int)(BSZ * NC), 256, 0, stream>>>(
                dlt, Bv, Cv, xc, zbuf, Alog_i, Dp + (size_t)i * ED, hloc,
                outproj_w + (size_t)i * DM * ED, outproj_b + (size_t)i * DM,
                hres, norm_w + (size_t)(i + 1) * DM,
                in_w + (size_t)(i + 1) * 2 * ED * DM,
                in_b + (size_t)(i + 1) * 2 * ED,
                hout, xin, zbuf);
            hres = hout;
        }
    }
}